// Round 6
// baseline (885.726 us; speedup 1.0000x reference)
//
#include <hip/hip_runtime.h>
#include <hip/hip_bf16.h>

// Fused 8-layer tanh RNN (B=4096, T=512, H=24, in=6) + final 24->3 FC.
//
// Layer-pipelined persistent-weight kernel.
//   wave l == layer l; 8 waves/block; NBB=2 batch elems/block; 2048 blocks.
//   lane = (b:0..1) x (jl:0..7) x (ks:0..3); per-lane 3j x 12k weight slab.
//   quad_perm DPP butterfly reduction; distributed tanh (lane ks=r -> j0+r).
//
// ROUND-5 CHANGES (attacking measured VALU-issue bound, 483 cyc/wave-phase):
//   1. v_pk_fma_f32 (VOP3P packed fp32): 36 scalar FMA -> 18 packed + 3 hadd
//      per slot. Scalar v_fma_f32 caps at half of the 157 TF fp32 peak.
//   2. TPP 2 -> 4: per-phase fixed costs (parity/bookkeeping/barrier) halve
//      per timestep; barriers 263 -> 135.

#define T_LEN  512
#define HD     24
#define NL     8
#define NBB    2
#define TPP    4
#define NPHASE (T_LEN / TPP + NL - 1)   // 135

// float strides in ibuf: j:1, b:24, sl:48, par:192, l:384
#define SL_STR  48
#define PAR_STR 192
#define L_STR   384

struct SMem {
    float ibuf[NL][2][TPP][NBB][HD];  // 3072 floats
    float pad[16];
    float hbuf[NL][NBB * HD + 16];    // 256B layer stride
};

typedef float v2f __attribute__((ext_vector_type(2)));

__device__ __forceinline__ v2f pk_fma(v2f a, v2f b, v2f c) {
    v2f d;
    asm("v_pk_fma_f32 %0, %1, %2, %3" : "=v"(d) : "v"(a), "v"(b), "v"(c));
    return d;
}

__device__ __forceinline__ float tanh_acc(float v) {
    // tanh(v) = 1 - 2/(exp(2v)+1); rcp refined by one Newton step (~1 ulp).
    float e = __expf(v + v);
    float d = e + 1.0f;
    float r = __builtin_amdgcn_rcpf(d);
    r = r * fmaf(-d, r, 2.0f);
    return fmaf(-2.0f, r, 1.0f);
}

// butterfly add across quad lanes: CTRL=0xB1 -> xor1, CTRL=0x4E -> xor2
template <int CTRL>
__device__ __forceinline__ float quad_bfly_add(float v) {
    int i = __builtin_bit_cast(int, v);
    int s = __builtin_amdgcn_update_dpp(i, i, CTRL, 0xF, 0xF, false);
    return v + __builtin_bit_cast(float, s);
}

__global__ __launch_bounds__(512) void rnn_fused_pipeline(
    const float* __restrict__ x,     // (4096, 512, 6)
    const float* __restrict__ Wih0,  // (24, 6)
    const float* __restrict__ WihR,  // (7, 24, 24)
    const float* __restrict__ Whh,   // (8, 24, 24)
    const float* __restrict__ bih,   // (8, 24)
    const float* __restrict__ bhh,   // (8, 24)
    const float* __restrict__ fcw,   // (3, 24)
    const float* __restrict__ fcb,   // (3,)
    float* __restrict__ out)         // (4096, 3)
{
    __shared__ __align__(128) SMem sm;

    const int tid  = threadIdx.x;
    const int l    = __builtin_amdgcn_readfirstlane(tid >> 6); // wave == layer
    const int lane = tid & 63;
    const int b    = lane >> 5;        // batch within block (0..1)
    const int jl   = (lane >> 2) & 7;  // j-trio
    const int ks   = lane & 3;         // k-quarter of concat [in(24)|h(24)]
    const int j0   = jl * 3;
    const int ks01 = ks & 1;           // 12-chunk within the half
    const int kh   = ks >> 1;          // 0: input half (Wih), 1: h half (Whh)

    // ---- zero-init LDS (h(-1)=0; x pad cols [6..23] stay 0 forever) ----
    {
        float* smf = (float*)&sm;
        for (int i = tid; i < (int)(sizeof(SMem) / 4); i += 512) smf[i] = 0.0f;
    }

    // ---- per-lane persistent weights: 3 j-rows x 12 k-cols, packed v2f ----
    v2f wp[3][6];
    #pragma unroll
    for (int s = 0; s < 3; ++s) {
        const int j = j0 + s;
        #pragma unroll
        for (int kk = 0; kk < 6; ++kk) {
            float wv[2];
            #pragma unroll
            for (int h2 = 0; h2 < 2; ++h2) {
                const int col = ks01 * 12 + kk * 2 + h2;
                if (kh == 0) {
                    if (l == 0) wv[h2] = (col < 6) ? Wih0[j * 6 + col] : 0.0f;
                    else        wv[h2] = WihR[((l - 1) * HD + j) * HD + col];
                } else {
                    wv[h2] = Whh[(l * HD + j) * HD + col];
                }
            }
            wp[s][kk] = (v2f){wv[0], wv[1]};
        }
    }
    // lane ks=r (r<3) finalizes output j0+r; bias folded post-reduction
    const int   bj    = j0 + ((ks == 3) ? 0 : ks);
    const float blane = bih[l * HD + bj] + bhh[l * HD + bj];

    const long bbase = (long)blockIdx.x * NBB;

    // ---- x prefetch mapping (wave 0, 48 lanes: 2b x 4sl x 6i) ----
    const bool isx = (l == 0) && (lane < NBB * 6 * TPP);
    const int  xbb = lane / (6 * TPP);
    const int  xrem = lane % (6 * TPP);
    const int  xsl = xrem / 6, xii = xrem % 6;
    const float* xp = x + ((bbase + xbb) * T_LEN + xsl) * 6 + xii;

    __syncthreads();  // zeros visible before x preload writes ibuf[0][1]

    if (isx) sm.ibuf[0][1][xsl][xbb][xii] = xp[0];   // t = xsl (0..3)
    __syncthreads();

    // ---- per-lane LDS pointers ----
    float* const ib    = &sm.ibuf[0][0][0][0][0];
    const float* base0 = ib + l * L_STR + b * HD + ks01 * 12;     // kh==0
    const float* baseH = &sm.hbuf[l][b * HD + ks01 * 12];         // kh==1
    const float* rd_p0 = kh ? baseH : base0;            // parity-0 read base
    const float* rd_p1 = kh ? baseH : base0 + PAR_STR;  // parity-1 read base
    const int    sloff = kh ? 0 : SL_STR;               // per-slot offset

    float*       hw = &sm.hbuf[l][b * HD + j0 + ks];              // ks<3 only
    float* const iw = ib + (l + 1) * L_STR + b * HD + j0 + ks;

    for (int ph = 0; ph < NPHASE; ++ph) {
        const int  pl     = ph - l;                        // uniform
        const bool active = (pl >= 0) && (pl < T_LEN / TPP);
        const int  rpar   = (ph + 1) & 1;
        const int  wpar   = ph & 1;
        const bool xgo    = isx && (ph < T_LEN / TPP - 1);

        // ---- wave 0: prefetch x for phase ph+1 (t = TPP*(ph+1)+xsl) ----
        float xv = 0.0f;
        if (xgo) xv = xp[6 * TPP * (ph + 1)];

        if (active) {
            const float* r0 = rpar ? rd_p1 : rd_p0;

            #pragma unroll
            for (int sl = 0; sl < TPP; ++sl) {
                const float4* src4 =
                    reinterpret_cast<const float4*>(r0 + sl * sloff);

                v2f acc0 = {0.f, 0.f}, acc1 = {0.f, 0.f}, acc2 = {0.f, 0.f};
                #pragma unroll
                for (int c = 0; c < 3; ++c) {        // 3x ds_read_b128
                    const float4 v4 = src4[c];
                    const v2f a01 = {v4.x, v4.y};
                    const v2f a23 = {v4.z, v4.w};
                    acc0 = pk_fma(wp[0][2 * c],     a01, acc0);
                    acc0 = pk_fma(wp[0][2 * c + 1], a23, acc0);
                    acc1 = pk_fma(wp[1][2 * c],     a01, acc1);
                    acc1 = pk_fma(wp[1][2 * c + 1], a23, acc1);
                    acc2 = pk_fma(wp[2][2 * c],     a01, acc2);
                    acc2 = pk_fma(wp[2][2 * c + 1], a23, acc2);
                }
                float s0 = acc0.x + acc0.y;          // horizontal (even+odd k)
                float s1 = acc1.x + acc1.y;
                float s2 = acc2.x + acc2.y;

                // quad butterfly: all 4 ks-lanes get the full 48-k sums
                s0 = quad_bfly_add<0xB1>(s0); s0 = quad_bfly_add<0x4E>(s0);
                s1 = quad_bfly_add<0xB1>(s1); s1 = quad_bfly_add<0x4E>(s1);
                s2 = quad_bfly_add<0xB1>(s2); s2 = quad_bfly_add<0x4E>(s2);

                // distributed tanh: lane ks=r finalizes output j0+r
                const float pre = (ks == 0) ? s0 : (ks == 1) ? s1 : s2;
                const float h   = tanh_acc(pre + blane);

                if (ks < 3) {
                    *hw = h;                                   // own h state
                    if (l < NL - 1)
                        iw[wpar * PAR_STR + sl * SL_STR] = h;  // feed layer l+1
                }

                if (sl + 1 < TPP) {
                    // same-wave LDS RAW (h(t) -> h(t+1)): drain DS queue,
                    // forbid reordering of next slot's reads upward.
                    asm volatile("s_waitcnt lgkmcnt(0)" ::: "memory");
                }
            }
        }

        // ---- wave 0: commit prefetched x into ibuf[0][wpar] ----
        if (xgo) sm.ibuf[0][wpar][xsl][xbb][xii] = xv;

        __syncthreads();  // one barrier per phase (4 timesteps)
    }

    // ---- FC epilogue: out[b] = fc_w @ h7(T-1) + fc_b ----
    if (tid < NBB * 3) {
        const int bb = tid / 3, k = tid % 3;
        float acc = fcb[k];
        #pragma unroll
        for (int j = 0; j < HD; ++j)
            acc = fmaf(fcw[k * HD + j], sm.hbuf[NL - 1][bb * HD + j], acc);
        out[(bbase + bb) * 3 + k] = acc;
    }
}

extern "C" void kernel_launch(void* const* d_in, const int* in_sizes, int n_in,
                              void* d_out, int out_size, void* d_ws, size_t ws_size,
                              hipStream_t stream) {
    const float* x    = (const float*)d_in[0];
    const float* Wih0 = (const float*)d_in[1];
    const float* WihR = (const float*)d_in[2];
    const float* Whh  = (const float*)d_in[3];
    const float* bih  = (const float*)d_in[4];
    const float* bhh  = (const float*)d_in[5];
    const float* fcw  = (const float*)d_in[6];
    const float* fcb  = (const float*)d_in[7];
    float* out = (float*)d_out;

    dim3 grid(4096 / NBB);   // 2048 blocks
    dim3 block(512);         // 8 waves: one per layer
    hipLaunchKernelGGL(rnn_fused_pipeline, grid, block, 0, stream,
                       x, Wih0, WihR, Whh, bih, bhh, fcw, fcb, out);
}

// Round 9
// 475.772 us; speedup vs baseline: 1.8617x; 1.8617x over previous
//
#include <hip/hip_runtime.h>
#include <hip/hip_bf16.h>

// Fused 8-layer tanh RNN (B=4096, T=512, H=24, in=6) + final 24->3 FC.
//
// ROUND-6/7/8: MFMA path. Per (t,layer) the op is a [4096]x[48]->[24]
// GEMM; batch is fully parallel. Structure:
//  - grid = 256 blocks (1/CU), block = 8 waves; wave l owns layer l
//    (layer-pipelined, skew 1 t/phase); block covers MB=16 batch rows.
//  - Math: D[m=batch16][n=j24] = A[m][k48+pad] * B[k][n] via
//    mfma_f32_16x16x32_bf16, hi/lo split: act = hi+lo (2x bf16),
//    w = whi+wlo; 3 MFMAs (hh, h*lo, lo*h; lo*lo dropped ~2^-18) x
//    2 k-tiles x 2 n-tiles = 12 MFMA / wave-slot.
//  - B-frags (weights+bias) persist in VGPRs (32 regs). Bias rides a
//    constant-1.0 A-slot (k-slot 31 of h planes) with B row 31 = bias.
//  - Activations in LDS bf16 planes P[par][9][16][40]: P[0]=x-in,
//    P[l+1]=layer-l h. Wave l reads ktile0 from P[l], ktile1 from P[l+1]
//    (own recurrent h + bias slot), writes tanh output to P[l+1].
//    Double-buffered by phase parity. Row stride 80B (16B-aligned b128
//    reads for all m).
//  - Verified layouts (learn_hip m89/m91/m97): A/B: lane&15=m/n,
//    k=(lane>>4)*8+i (8 contiguous bf16 = 1 ds_read_b128);
//    C/D: col=lane&15, row=(lane>>4)*4+reg.

#define T_LEN 512
#define HD    24
#define NL    8
#define MB    16
#define NPH   (T_LEN + NL - 1)   // 519
#define ROWS  40                 // shorts/row: 32 k-slots + 8 pad = 80 B

typedef __bf16 bf16x8 __attribute__((ext_vector_type(8)));
typedef float  f32x4  __attribute__((ext_vector_type(4)));
typedef short  s16x8  __attribute__((ext_vector_type(8)));

__device__ __forceinline__ f32x4 mfma16(bf16x8 a, bf16x8 b, f32x4 c) {
    return __builtin_amdgcn_mfma_f32_16x16x32_bf16(a, b, c, 0, 0, 0);
}

__device__ __forceinline__ float tanh_acc(float v) {
    // tanh(v) = 1 - 2/(exp(2v)+1); rcp + one Newton step (~1 ulp).
    float e = __expf(v + v);
    float d = e + 1.0f;
    float r = __builtin_amdgcn_rcpf(d);
    r = r * fmaf(-d, r, 2.0f);
    return fmaf(-2.0f, r, 1.0f);
}

__device__ __forceinline__ unsigned short bfbits(float v) {
    return __builtin_bit_cast(unsigned short, (__bf16)v);
}
__device__ __forceinline__ float bf2f(unsigned short u) {
    unsigned int w = ((unsigned int)u) << 16;
    return __builtin_bit_cast(float, w);
}

__global__ __launch_bounds__(512) void rnn_mfma_pipeline(
    const float* __restrict__ x,     // (4096, 512, 6)
    const float* __restrict__ Wih0,  // (24, 6)
    const float* __restrict__ WihR,  // (7, 24, 24)
    const float* __restrict__ Whh,   // (8, 24, 24)
    const float* __restrict__ bih,   // (8, 24)
    const float* __restrict__ bhh,   // (8, 24)
    const float* __restrict__ fcw,   // (3, 24)
    const float* __restrict__ fcb,   // (3,)
    float* __restrict__ out)         // (4096, 3)
{
    __shared__ unsigned short Phi[2][NL + 1][MB][ROWS];
    __shared__ unsigned short Plo[2][NL + 1][MB][ROWS];

    const int tid  = threadIdx.x;
    const int l    = __builtin_amdgcn_readfirstlane(tid >> 6);  // wave == layer
    const int lane = tid & 63;
    const int m    = lane & 15;   // A row / C col index
    const int kg   = lane >> 4;   // k-group (0..3)

    // ---- zero LDS, set constant-1.0 bias slots (k-slot 31 of h planes) ----
    {
        unsigned short* ph = &Phi[0][0][0][0];
        unsigned short* pl = &Plo[0][0][0][0];
        const int TOT = 2 * (NL + 1) * MB * ROWS;
        for (int i = tid; i < TOT; i += 512) { ph[i] = 0; pl[i] = 0; }
    }
    __syncthreads();
    for (int i = tid; i < 2 * NL * MB; i += 512) {
        const int par = i & 1;
        const int pli = (i >> 1) % NL;
        const int mm  = (i >> 1) / NL;
        Phi[par][pli + 1][mm][31] = 0x3F80;   // bf16(1.0)
    }

    // ---- persistent B-fragments (weights, wave l) ----
    // B[k][n] = W[n][k]; lane: n = nt*16 + (lane&15), k = kg*8 + i.
    bf16x8 Bh[2][2], Bl[2][2];
    #pragma unroll
    for (int nt = 0; nt < 2; ++nt) {
        const int n = nt * 16 + m;
        #pragma unroll
        for (int kt = 0; kt < 2; ++kt) {
            bf16x8 fh, fl;
            #pragma unroll
            for (int i = 0; i < 8; ++i) {
                const int k = kg * 8 + i;
                float wv = 0.0f;
                if (n < HD) {
                    if (kt == 0) {
                        if (l == 0) { if (k < 6)  wv = Wih0[n * 6 + k]; }
                        else        { if (k < HD) wv = WihR[((l - 1) * HD + n) * HD + k]; }
                    } else {
                        if (k < HD)       wv = Whh[(l * HD + n) * HD + k];
                        else if (k == 31) wv = bih[l * HD + n] + bhh[l * HD + n];
                    }
                }
                const __bf16 hv = (__bf16)wv;
                fh[i] = hv;
                fl[i] = (__bf16)(wv - (float)hv);
            }
            Bh[nt][kt] = fh; Bl[nt][kt] = fl;
        }
    }

    const long bbase = (long)blockIdx.x * MB;

    // ---- x staging mapping (wave 0, lanes 0..47: 2 values each) ----
    const bool isx = (l == 0) && (lane < 48);
    const int  xb  = lane / 6;          // batch 0..7 (and +8 for 2nd value)
    const int  xi  = lane % 6;
    const float* xp0 = x + ((bbase + xb)     * T_LEN) * 6 + xi;
    const float* xp1 = x + ((bbase + xb + 8) * T_LEN) * 6 + xi;

    // preload x(t=0) into parity 1 (read parity of phase 0)
    if (isx) {
        const float v0 = xp0[0], v1 = xp1[0];
        Phi[1][0][xb][xi]     = bfbits(v0);
        Plo[1][0][xb][xi]     = bfbits(v0 - bf2f(bfbits(v0)));
        Phi[1][0][xb + 8][xi] = bfbits(v1);
        Plo[1][0][xb + 8][xi] = bfbits(v1 - bf2f(bfbits(v1)));
    }
    __syncthreads();

    for (int p = 0; p < NPH; ++p) {
        const int  pl_    = p - l;                       // wave-uniform
        const bool active = (pl_ >= 0) && (pl_ < T_LEN);
        const int  rpar   = (p + 1) & 1;                 // read parity
        const int  wpar   = p & 1;                       // write parity
        const bool xgo    = isx && (p + 1 < T_LEN);

        // issue x global loads early (hide L3 latency under MFMA work)
        float xv0 = 0.f, xv1 = 0.f;
        if (xgo) { xv0 = xp0[(p + 1) * 6]; xv1 = xp1[(p + 1) * 6]; }

        if (active) {
            // A-fragments: ktile0 = input plane P[l], ktile1 = own-h P[l+1]
            const bf16x8 Ah0 = __builtin_bit_cast(bf16x8,
                *(const s16x8*)&Phi[rpar][l][m][kg * 8]);
            const bf16x8 Ah1 = __builtin_bit_cast(bf16x8,
                *(const s16x8*)&Phi[rpar][l + 1][m][kg * 8]);
            const bf16x8 Al0 = __builtin_bit_cast(bf16x8,
                *(const s16x8*)&Plo[rpar][l][m][kg * 8]);
            const bf16x8 Al1 = __builtin_bit_cast(bf16x8,
                *(const s16x8*)&Plo[rpar][l + 1][m][kg * 8]);

            f32x4 acc0 = {0.f, 0.f, 0.f, 0.f};
            f32x4 acc1 = {0.f, 0.f, 0.f, 0.f};
            // hi*hi + hi*lo + lo*hi  (lo*lo dropped, ~2^-18 rel)
            acc0 = mfma16(Ah0, Bh[0][0], acc0);
            acc1 = mfma16(Ah0, Bh[1][0], acc1);
            acc0 = mfma16(Ah1, Bh[0][1], acc0);
            acc1 = mfma16(Ah1, Bh[1][1], acc1);
            acc0 = mfma16(Ah0, Bl[0][0], acc0);
            acc1 = mfma16(Ah0, Bl[1][0], acc1);
            acc0 = mfma16(Ah1, Bl[0][1], acc0);
            acc1 = mfma16(Ah1, Bl[1][1], acc1);
            acc0 = mfma16(Al0, Bh[0][0], acc0);
            acc1 = mfma16(Al0, Bh[1][0], acc1);
            acc0 = mfma16(Al1, Bh[0][1], acc0);
            acc1 = mfma16(Al1, Bh[1][1], acc1);

            // tanh + hi/lo split + b16 writes to own h plane
            #pragma unroll
            for (int nt = 0; nt < 2; ++nt) {
                const f32x4 c = nt ? acc1 : acc0;
                #pragma unroll
                for (int r = 0; r < 4; ++r) {
                    const float h  = tanh_acc(c[r]);
                    const __bf16 hh = (__bf16)h;
                    const float  hf = (float)hh;
                    const int    mm = kg * 4 + r;       // C row = batch
                    if (nt == 0 || m < 8) {
                        const int j = nt * 16 + m;      // C col = output j
                        Phi[wpar][l + 1][mm][j] = __builtin_bit_cast(unsigned short, hh);
                        Plo[wpar][l + 1][mm][j] = bfbits(h - hf);
                    }
                }
            }
        }

        // commit x(t=p+1) into P[0][wpar] (read next phase by wave 0)
        if (xgo) {
            Phi[wpar][0][xb][xi]     = bfbits(xv0);
            Plo[wpar][0][xb][xi]     = bfbits(xv0 - bf2f(bfbits(xv0)));
            Phi[wpar][0][xb + 8][xi] = bfbits(xv1);
            Plo[wpar][0][xb + 8][xi] = bfbits(xv1 - bf2f(bfbits(xv1)));
        }

        __syncthreads();
    }

    // ---- FC epilogue: out = fc_w @ h7(T-1) + fc_b ----
    // wave 7 wrote t=511 at phase 518 -> parity 0.
    if (l == 0 && lane < MB * 3) {
        const int b = lane / 3, k = lane % 3;
        float acc = fcb[k];
        #pragma unroll
        for (int j = 0; j < HD; ++j) {
            const float hj = bf2f(Phi[0][NL][b][j]) + bf2f(Plo[0][NL][b][j]);
            acc = fmaf(fcw[k * HD + j], hj, acc);
        }
        out[(bbase + b) * 3 + k] = acc;
    }
}

extern "C" void kernel_launch(void* const* d_in, const int* in_sizes, int n_in,
                              void* d_out, int out_size, void* d_ws, size_t ws_size,
                              hipStream_t stream) {
    const float* x    = (const float*)d_in[0];
    const float* Wih0 = (const float*)d_in[1];
    const float* WihR = (const float*)d_in[2];
    const float* Whh  = (const float*)d_in[3];
    const float* bih  = (const float*)d_in[4];
    const float* bhh  = (const float*)d_in[5];
    const float* fcw  = (const float*)d_in[6];
    const float* fcb  = (const float*)d_in[7];
    float* out = (float*)d_out;

    dim3 grid(4096 / MB);   // 256 blocks = 1 per CU
    dim3 block(512);        // 8 waves: one per layer
    hipLaunchKernelGGL(rnn_mfma_pipeline, grid, block, 0, stream,
                       x, Wih0, WihR, Whh, bih, bhh, fcw, fcb, out);
}